// Round 1
// baseline (467.575 us; speedup 1.0000x reference)
//
#include <hip/hip_runtime.h>
#include <hip/hip_bf16.h>

// LengthRegulator: out[b,t,:] = x[b, searchsorted_right(cum[b], t).clip(0,L-1), :]
//                  masked to 0 where t >= cum[b, L-1].
// B=32, L=1024, D=384, MAX_LEN=8192. fp32 in/out.
// Memory-bound: 403 MB write floor => ~64 us at 6.3 TB/s.

#define L_FIXED 1024
#define TILE_T 128
#define ROW_F4 96   // 384 floats / 4

// Kernel 1: per-batch inclusive cumsum of round(clip(dur,0)).
// One block of 1024 threads per batch; Hillis-Steele scan in LDS.
__global__ __launch_bounds__(1024) void lr_cumsum_kernel(
    const float* __restrict__ durations, int* __restrict__ cum, int L) {
    __shared__ int s[L_FIXED];
    const int b = blockIdx.x;
    const int tid = threadIdx.x;
    float d = durations[b * L + tid];
    // jnp.round = half-to-even; rintf uses RN (half-to-even) by default.
    s[tid] = (int)rintf(fmaxf(d, 0.0f));
    __syncthreads();
#pragma unroll
    for (int off = 1; off < L_FIXED; off <<= 1) {
        int add = (tid >= off) ? s[tid - off] : 0;
        __syncthreads();
        s[tid] += add;
        __syncthreads();
    }
    cum[b * L + tid] = s[tid];
}

// Kernel 2: gather + mask. Block = 256 threads handles TILE_T output rows
// of one batch. cum for the batch staged in LDS (4 KB); 10-step binary
// search per row; float4 coalesced copy of the rows.
__global__ __launch_bounds__(256) void lr_gather_kernel(
    const float4* __restrict__ x, const int* __restrict__ cum,
    float4* __restrict__ out, int L, int max_len) {
    __shared__ int s_cum[L_FIXED];
    __shared__ int s_idx[TILE_T];
    const int b = blockIdx.y;
    const int t0 = blockIdx.x * TILE_T;
    const int tid = threadIdx.x;

    for (int i = tid; i < L; i += 256) s_cum[i] = cum[b * L + i];
    __syncthreads();

    const int total = s_cum[L - 1];
    if (tid < TILE_T) {
        const int t = t0 + tid;
        // searchsorted(cum, t, side='right'): first i with cum[i] > t
        int lo = 0, hi = L;
        while (lo < hi) {
            int mid = (lo + hi) >> 1;
            if (s_cum[mid] <= t) lo = mid + 1; else hi = mid;
        }
        int idx = min(lo, L - 1);
        s_idx[tid] = (t < total) ? idx : -1;
    }
    __syncthreads();

    const long out_base = ((long)b * max_len + t0) * ROW_F4;
    const long x_base = (long)b * L * ROW_F4;
#pragma unroll
    for (int j = tid; j < TILE_T * ROW_F4; j += 256) {
        const int tl = j / ROW_F4;
        const int c = j - tl * ROW_F4;
        const int row = s_idx[tl];
        float4 v;
        if (row >= 0) {
            v = x[x_base + (long)row * ROW_F4 + c];
        } else {
            v = make_float4(0.f, 0.f, 0.f, 0.f);
        }
        out[out_base + (long)tl * ROW_F4 + c] = v;
    }
}

extern "C" void kernel_launch(void* const* d_in, const int* in_sizes, int n_in,
                              void* d_out, int out_size, void* d_ws, size_t ws_size,
                              hipStream_t stream) {
    const float* x = (const float*)d_in[0];          // (B, L, D) fp32
    const float* durations = (const float*)d_in[1];  // (B, L) fp32
    // d_in[2] = max_len scalar (host constant 8192; value known from reference)

    const int B = 32;
    const int L = 1024;
    const int MAX_LEN = 8192;

    int* cum = (int*)d_ws;  // B*L ints = 128 KB scratch

    lr_cumsum_kernel<<<B, L_FIXED, 0, stream>>>(durations, cum, L);

    dim3 grid(MAX_LEN / TILE_T, B);
    lr_gather_kernel<<<grid, 256, 0, stream>>>(
        (const float4*)x, cum, (float4*)d_out, L, MAX_LEN);
}

// Round 2
// 454.155 us; speedup vs baseline: 1.0295x; 1.0295x over previous
//
#include <hip/hip_runtime.h>
#include <hip/hip_bf16.h>

// LengthRegulator: out[b,t,:] = x[b, searchsorted_right(cum[b], t).clip(0,L-1), :]
//                  masked to 0 where t >= cum[b, L-1].
// B=32, L=1024, D=384, MAX_LEN=8192. fp32 in/out.
// Roofline: 403 MB write (+ ~50 MB x read, L3-resident) => ~70 us at 6.3 TB/s.
//
// R2: split into (A) fused scan+searchsorted -> idx[b][t] in ws, and
// (B) streaming copy with (96,4) block: row = threadIdx.y-derived, no div,
// no unroll pragma (R1's 48-way unroll likely spilled -> ~1 TB/s effective).

#define B_FIXED 32
#define L_FIXED 1024
#define ROW_F4 96        // 384 floats / 4
#define RPB 32           // output rows per copy block

// Kernel A: per-batch inclusive scan of round(clip(dur,0)) in LDS, then
// searchsorted_right for all t in [0, max_len). idx = -1 where masked.
__global__ __launch_bounds__(1024) void lr_scan_idx_kernel(
    const float* __restrict__ durations, int* __restrict__ idx, int max_len) {
    __shared__ int s[L_FIXED];
    const int b = blockIdx.x;
    const int tid = threadIdx.x;
    float d = durations[b * L_FIXED + tid];
    s[tid] = (int)rintf(fmaxf(d, 0.0f));   // jnp.round = half-to-even = rintf
    __syncthreads();
    for (int off = 1; off < L_FIXED; off <<= 1) {
        int add = (tid >= off) ? s[tid - off] : 0;
        __syncthreads();
        s[tid] += add;
        __syncthreads();
    }
    const int total = s[L_FIXED - 1];
    for (int t = tid; t < max_len; t += 1024) {
        // first i with s[i] > t
        int lo = 0, hi = L_FIXED;
        while (lo < hi) {
            int mid = (lo + hi) >> 1;
            if (s[mid] <= t) lo = mid + 1; else hi = mid;
        }
        int v = min(lo, L_FIXED - 1);
        idx[b * max_len + t] = (t < total) ? v : -1;
    }
}

// Kernel B: pure streaming gather-copy. Block (96,4): x-lane = float4 column,
// y = row within tile. Coalesced 16B/lane loads and stores, no division.
__global__ __launch_bounds__(384) void lr_copy_kernel(
    const float4* __restrict__ x, const int* __restrict__ idx,
    float4* __restrict__ out, int max_len) {
    __shared__ int s_idx[RPB];
    const int b = blockIdx.y;
    const int t0 = blockIdx.x * RPB;
    const int lin = threadIdx.y * 96 + threadIdx.x;
    if (lin < RPB) s_idx[lin] = idx[b * max_len + t0 + lin];
    __syncthreads();

    const long xbase = (long)b * L_FIXED * ROW_F4;
    const long obase = ((long)b * max_len + t0) * ROW_F4;
    const int cx = threadIdx.x;
    for (int r = threadIdx.y; r < RPB; r += 4) {
        const int row = s_idx[r];
        float4 v;
        if (row >= 0) {
            v = x[xbase + (long)row * ROW_F4 + cx];
        } else {
            v = make_float4(0.f, 0.f, 0.f, 0.f);
        }
        out[obase + (long)r * ROW_F4 + cx] = v;
    }
}

extern "C" void kernel_launch(void* const* d_in, const int* in_sizes, int n_in,
                              void* d_out, int out_size, void* d_ws, size_t ws_size,
                              hipStream_t stream) {
    const float* x = (const float*)d_in[0];          // (B, L, D) fp32
    const float* durations = (const float*)d_in[1];  // (B, L) fp32
    const int MAX_LEN = 8192;

    int* idx = (int*)d_ws;  // B * MAX_LEN ints = 1 MB scratch

    lr_scan_idx_kernel<<<B_FIXED, 1024, 0, stream>>>(durations, idx, MAX_LEN);

    dim3 grid(MAX_LEN / RPB, B_FIXED);
    dim3 block(96, 4);
    lr_copy_kernel<<<grid, block, 0, stream>>>(
        (const float4*)x, idx, (float4*)d_out, MAX_LEN);
}

// Round 4
// 439.341 us; speedup vs baseline: 1.0643x; 1.0337x over previous
//
#include <hip/hip_runtime.h>
#include <hip/hip_bf16.h>

// LengthRegulator: out[b,t,:] = x[b, searchsorted_right(cum[b], t).clip(0,L-1), :]
//                  masked to 0 where t >= cum[b, L-1].
// B=32, L=1024, D=384, MAX_LEN=8192. fp32 in/out.
// Floor for OUR kernels: 403 MB write + ~50 MB cold read => ~72 us at 6.3 TB/s.
// NOTE: bench dur_us includes ~270 us of harness poison-fill/restore per iter.
//
// R4: same as R3 but with clang ext_vector_type float4 so
// __builtin_nontemporal_store compiles (HIP_vector_type is a class -> rejected).

#define B_FIXED 32
#define L_FIXED 1024
#define ROW_F4 96        // 384 floats / 4
#define RPB 32           // output rows per copy block

typedef float vfloat4 __attribute__((ext_vector_type(4)));

// Kernel A: per-batch inclusive scan of round(clip(dur,0)) in LDS, then
// searchsorted_right for all t in [0, max_len). idx = -1 where masked.
__global__ __launch_bounds__(1024) void lr_scan_idx_kernel(
    const float* __restrict__ durations, int* __restrict__ idx, int max_len) {
    __shared__ int s[L_FIXED];
    const int b = blockIdx.x;
    const int tid = threadIdx.x;
    float d = durations[b * L_FIXED + tid];
    s[tid] = (int)rintf(fmaxf(d, 0.0f));   // jnp.round = half-to-even = rintf
    __syncthreads();
    for (int off = 1; off < L_FIXED; off <<= 1) {
        int add = (tid >= off) ? s[tid - off] : 0;
        __syncthreads();
        s[tid] += add;
        __syncthreads();
    }
    const int total = s[L_FIXED - 1];
    for (int t = tid; t < max_len; t += 1024) {
        // first i with s[i] > t
        int lo = 0, hi = L_FIXED;
        while (lo < hi) {
            int mid = (lo + hi) >> 1;
            if (s[mid] <= t) lo = mid + 1; else hi = mid;
        }
        int v = min(lo, L_FIXED - 1);
        idx[b * max_len + t] = (t < total) ? v : -1;
    }
}

// Kernel B: streaming gather-copy. Block (96,4): x-lane = float4 column,
// y = row phase. Two rows in flight per iteration; nontemporal stores.
__global__ __launch_bounds__(384) void lr_copy_kernel(
    const vfloat4* __restrict__ x, const int* __restrict__ idx,
    vfloat4* __restrict__ out, int max_len) {
    __shared__ int s_idx[RPB];
    const int b = blockIdx.y;
    const int t0 = blockIdx.x * RPB;
    const int lin = threadIdx.y * 96 + threadIdx.x;
    if (lin < RPB) s_idx[lin] = idx[b * max_len + t0 + lin];
    __syncthreads();

    const long xbase = (long)b * L_FIXED * ROW_F4;
    const long obase = ((long)b * max_len + t0) * ROW_F4;
    const int cx = threadIdx.x;
    const int y  = threadIdx.y;
    const vfloat4 zero = {0.f, 0.f, 0.f, 0.f};

#pragma unroll
    for (int k = 0; k < 4; ++k) {
        const int ra = y + 8 * k;
        const int rb = ra + 4;
        const int rowa = s_idx[ra];
        const int rowb = s_idx[rb];
        vfloat4 va = zero, vb = zero;
        if (rowa >= 0) va = x[xbase + (long)rowa * ROW_F4 + cx];
        if (rowb >= 0) vb = x[xbase + (long)rowb * ROW_F4 + cx];
        __builtin_nontemporal_store(va, &out[obase + (long)ra * ROW_F4 + cx]);
        __builtin_nontemporal_store(vb, &out[obase + (long)rb * ROW_F4 + cx]);
    }
}

extern "C" void kernel_launch(void* const* d_in, const int* in_sizes, int n_in,
                              void* d_out, int out_size, void* d_ws, size_t ws_size,
                              hipStream_t stream) {
    const float* x = (const float*)d_in[0];          // (B, L, D) fp32
    const float* durations = (const float*)d_in[1];  // (B, L) fp32
    const int MAX_LEN = 8192;

    int* idx = (int*)d_ws;  // B * MAX_LEN ints = 1 MB scratch

    lr_scan_idx_kernel<<<B_FIXED, 1024, 0, stream>>>(durations, idx, MAX_LEN);

    dim3 grid(MAX_LEN / RPB, B_FIXED);
    dim3 block(96, 4);
    lr_copy_kernel<<<grid, block, 0, stream>>>(
        (const vfloat4*)x, idx, (vfloat4*)d_out, MAX_LEN);
}